// Round 4
// baseline (289.677 us; speedup 1.0000x reference)
//
#include <hip/hip_runtime.h>

#define DTC 0.2f
#define EPSC 1e-8f

// ws float layout:
//   [0..7]    dlf[j]  (dl-MLP output per neighbor slot, bo folded in)
//   family f in {an=0, rn=1, rb=2} at base B=16+f*112:
//     [B..B+31]    sorted knots t = -bi/wi  (ascending)
//     [B+32..B+64] SufW[i] = sum_{m>=i} wi*wo over sorted order (SufW[32]=0)
//     [B+65..B+97] SufB[i] = sum_{m>=i} wo*bi                  (SufB[32]=0)
// mono(x) = -(SufW[i]*x + SufB[i]) + bo,  i = #{knots <= x}  (5-step search)

__global__ __launch_bounds__(128) void sfm_pre(
    const float* __restrict__ ego,
    const float* __restrict__ an_wi, const float* __restrict__ an_bi, const float* __restrict__ an_wo,
    const float* __restrict__ rn_wi, const float* __restrict__ rn_bi, const float* __restrict__ rn_wo,
    const float* __restrict__ rb_wi, const float* __restrict__ rb_bi, const float* __restrict__ rb_wo,
    const float* __restrict__ dl_wi, const float* __restrict__ dl_bi,
    const float* __restrict__ dl_wo, const float* __restrict__ dl_bo,
    float* __restrict__ ws)
{
    __shared__ float tk[96], wiwo[96], wobi[96], skn[96], ssw[96], ssb[96];
    int t = threadIdx.x;
    if (t < 96) {
        int f = t >> 5, k = t & 31;
        const float* wip = (f == 0) ? an_wi : ((f == 1) ? rn_wi : rb_wi);
        const float* bip = (f == 0) ? an_bi : ((f == 1) ? rn_bi : rb_bi);
        const float* wop = (f == 0) ? an_wo : ((f == 1) ? rn_wo : rb_wo);
        float wi = wip[k], bi = bip[k], wo = wop[k];
        tk[t]   = -bi / wi;
        wiwo[t] = wi * wo;
        wobi[t] = wo * bi;
    }
    __syncthreads();
    if (t < 96) {
        int f = t >> 5, k = t & 31;
        float my = tk[t];
        int rank = 0;
        for (int m = 0; m < 32; ++m) {
            float o = tk[f * 32 + m];
            rank += (o < my || (o == my && m < k)) ? 1 : 0;
        }
        skn[f * 32 + rank] = my;
        ssw[f * 32 + rank] = wiwo[t];
        ssb[f * 32 + rank] = wobi[t];
    }
    __syncthreads();
    if (t < 96) {
        int f = t >> 5, p = t & 31;
        float sw_ = 0.f, sb_ = 0.f;
        for (int m = p; m < 32; ++m) { sw_ += ssw[f * 32 + m]; sb_ += ssb[f * 32 + m]; }
        int base = 16 + f * 112;
        ws[base + p]      = skn[f * 32 + p];
        ws[base + 32 + p] = sw_;
        ws[base + 65 + p] = sb_;
        if (p == 0) { ws[base + 64] = 0.f; ws[base + 97] = 0.f; }
    }
    if (t >= 96 && t < 104) {
        int j = t - 96;
        const float* base = ego + 51;
        float idv = base[2 * 17 + 8 + j];
        float dur = 0.f;
        for (int tt = 0; tt < 3; ++tt) {
            bool fo = false;
            for (int m = 0; m < 8; ++m) fo = fo || (idv == base[tt * 17 + 8 + m]);
            dur += fo ? 1.f : 0.f;
        }
        float acc = 0.f;
        for (int k = 0; k < 32; ++k)
            acc = fmaf(dl_wo[k], fmaxf(0.f, -fmaf(dl_wi[k], dur, dl_bi[k])), acc);
        ws[j] = acc + dl_bo[0];
    }
}

__device__ __forceinline__ float mono_eval(const float* __restrict__ kn, float x) {
    int i = (kn[15] <= x) ? 16 : 0;
    i += (kn[i + 7] <= x) ? 8 : 0;
    i += (kn[i + 3] <= x) ? 4 : 0;
    i += (kn[i + 1] <= x) ? 2 : 0;
    i += (kn[i] <= x) ? 1 : 0;
    return -fmaf(kn[32 + i], x, kn[65 + i]);
}

// ---------------------------------------------------------------------------
// Main: 256 threads = 32 rows, 8 lanes/row. Full rows staged through LDS with
// coalesced float4 global loads; all gathers become LDS reads.
// ---------------------------------------------------------------------------
__global__ __launch_bounds__(256) void sfm_main(
    const float* __restrict__ ego, const float* __restrict__ nei,
    const float* __restrict__ border, const float* __restrict__ adp,
    const float* __restrict__ eang,
    const float* __restrict__ an_bo, const float* __restrict__ rn_bo,
    const float* __restrict__ rb_bo,
    const float* __restrict__ wsrc,
    float* __restrict__ out, int Bn)
{
    __shared__ float sw[360];
    __shared__ float snei[4352];   // 32 rows x 136 floats
    __shared__ float sego[1632];   // 32 rows x 51 floats
    __shared__ float sout[192];    // 32 rows x 6 floats

    int t = threadIdx.x;
    long long blk = blockIdx.x;

    // ---- coalesced staging -------------------------------------------------
    {
        const float4* nsrc = (const float4*)nei + blk * 1088;
        long long ntot = (long long)Bn * 34;            // total float4s in nei
        float4* nd = (float4*)snei;
#pragma unroll
        for (int i = 0; i < 5; ++i) {
            int idx = t + 256 * i;
            if (idx < 1088 && blk * 1088 + idx < ntot) nd[idx] = nsrc[idx];
        }
        const float4* esrc = (const float4*)ego + blk * 408;
        long long etot = (long long)Bn * 51 / 4;
        float4* ed = (float4*)sego;
#pragma unroll
        for (int i = 0; i < 2; ++i) {
            int idx = t + 256 * i;
            if (idx < 408 && blk * 408 + idx < etot) ed[idx] = esrc[idx];
        }
    }
    for (int i = t; i < 352; i += 256) sw[i] = wsrc[i];
    if (t == 0) sw[352] = an_bo[0];
    if (t == 1) sw[353] = rn_bo[0];
    if (t == 2) sw[354] = rb_bo[0];
    if (t == 3) sw[355] = adp[0];
    if (t == 4) sw[356] = adp[1];
    if (t == 5) sw[357] = eang[0];
    if (t == 6) sw[358] = border[0];
    if (t == 7) sw[359] = border[3];
    __syncthreads();

    int l  = t & 7;          // neighbor slot
    int r32 = t >> 3;        // row within block

    // ego fields (LDS broadcast within each 8-lane group)
    const float* eg = sego + 51 * r32 + 34;
    float g0 = eg[0], g1 = eg[1], g2 = eg[2], g3 = eg[3], g4 = eg[4], g5 = eg[5];

    // this lane's neighbor record fields 2..5
    const float* nr = snei + 136 * r32 + 17 * l + 2;
    float nx = nr[0], ny = nr[1], vx = nr[2], vy = nr[3];

    float Rx = nx - g2, Ry = ny - g3;
    float rr = sqrtf(Rx * Rx + Ry * Ry);
    float ax = fmaf(vx, DTC, Rx), ay = fmaf(vy, DTC, Ry);
    float wx = vx * DTC, wy = vy * DTC;
    float bb = sqrtf(rr + ax * ax + ay * ay - wx * wx - wy * wy) * 0.5f;

    float an_bo_v = sw[352], rn_bo_v = sw[353], rb_bo_v = sw[354];
    float p0 = sw[355], p1 = sw[356], ang = sw[357];
    float rb0 = g3 - sw[358], rb1 = g3 - sw[359];
    float rbn0 = fabsf(rb0), rbn1 = fabsf(rb1);

    // MLP evals via knot search (bases: an=16, rn=128, rb=240)
    float fA = mono_eval(sw + 16, rr) + an_bo_v;
    float fR = mono_eval(sw + 128, bb) + rn_bo_v;
    float xb = (l == 1) ? rbn1 : rbn0;
    float vB = 0.f;
    if (l < 2) vB = mono_eval(sw + 240, xb) + rb_bo_v;
    int lb = (t & 63) & ~7;
    float vB0 = __shfl(vB, lb + 0, 64);
    float vB1 = __shfl(vB, lb + 1, 64);

    // e = normalize(ego_last[4:6])
    float elen = sqrtf(g4 * g4 + g5 * g5);
    float ex = g4 / elen, ey = g5 / elen;
    float na = fmaxf(sqrtf(ex * ex + ey * ey), EPSC);

    float axs = 0.f, ays = 0.f;
#define CLAMP_ADD(VX, VY)                                                   \
    {                                                                       \
        float _vx = (VX), _vy = (VY);                                       \
        float _nv = fmaxf(sqrtf(_vx * _vx + _vy * _vy), EPSC);              \
        float _c = (ex * _vx + ey * _vy) / (na * _nv);                      \
        if (fabsf(_c) > ang) { axs += _vx; ays += _vy; }                    \
    }

    float mfx = (nx == 0.f) ? 0.f : 1.f;
    float mfy = (ny == 0.f) ? 0.f : 1.f;

    { // f_attr for this record
        float coef = fA / rr * sw[l];               // dlf factor
        CLAMP_ADD(coef * Rx * mfx, coef * Ry * mfy);
    }
    { // f_repu for this record
        float coef = fR / rr;
        CLAMP_ADD(coef * Rx * mfx, coef * Ry * mfy);
    }

    // reduce over the 8 lanes of the row
#pragma unroll
    for (int m = 1; m < 8; m <<= 1) {
        axs += __shfl_xor(axs, m, 64);
        ays += __shfl_xor(ays, m, 64);
    }

    if (l == 0) {
        // f_dest
        float dvn = sqrtf(g3 * g3 + g4 * g4);
        CLAMP_ADD((p1 * dvn - g3) / p0, -g4 / p0);
        // f_bor
        CLAMP_ADD(0.f, vB0 * (rb0 / rbn0));
        CLAMP_ADD(0.f, vB1 * (rb1 / rbn1));

        float vxo = fmaf(axs, DTC, g2);
        float vyo = fmaf(ays, DTC, g3);
        float* op = sout + 6 * r32;
        op[0] = fmaf(vxo, DTC, g0);
        op[1] = fmaf(vyo, DTC, g1);
        op[2] = vxo; op[3] = vyo;
        op[4] = axs; op[5] = ays;
    }
#undef CLAMP_ADD

    __syncthreads();
    // coalesced output store: 192 consecutive floats per block
    if (t < 192) {
        long long o = blk * 192 + t;
        if (o < (long long)Bn * 6) out[o] = sout[t];
    }
}

extern "C" void kernel_launch(void* const* d_in, const int* in_sizes, int n_in,
                              void* d_out, int out_size, void* d_ws, size_t ws_size,
                              hipStream_t stream) {
    const float* ego    = (const float*)d_in[0];
    const float* nei    = (const float*)d_in[1];
    const float* border = (const float*)d_in[2];
    const float* adp    = (const float*)d_in[3];
    const float* eang   = (const float*)d_in[4];
    const float* an_wi  = (const float*)d_in[5];
    const float* an_bi  = (const float*)d_in[6];
    const float* an_wo  = (const float*)d_in[7];
    const float* an_bo  = (const float*)d_in[8];
    const float* rn_wi  = (const float*)d_in[9];
    const float* rn_bi  = (const float*)d_in[10];
    const float* rn_wo  = (const float*)d_in[11];
    const float* rn_bo  = (const float*)d_in[12];
    const float* rb_wi  = (const float*)d_in[13];
    const float* rb_bi  = (const float*)d_in[14];
    const float* rb_wo  = (const float*)d_in[15];
    const float* rb_bo  = (const float*)d_in[16];
    const float* dl_wi  = (const float*)d_in[17];
    const float* dl_bi  = (const float*)d_in[18];
    const float* dl_wo  = (const float*)d_in[19];
    const float* dl_bo  = (const float*)d_in[20];
    float* out = (float*)d_out;
    float* ws  = (float*)d_ws;

    int Bn = in_sizes[0] / (3 * 17);

    sfm_pre<<<1, 128, 0, stream>>>(ego,
                                   an_wi, an_bi, an_wo,
                                   rn_wi, rn_bi, rn_wo,
                                   rb_wi, rb_bi, rb_wo,
                                   dl_wi, dl_bi, dl_wo, dl_bo, ws);

    int grid = (Bn + 31) / 32;
    sfm_main<<<grid, 256, 0, stream>>>(ego, nei, border, adp, eang,
                                       an_bo, rn_bo, rb_bo,
                                       ws, out, Bn);
}

// Round 5
// 284.112 us; speedup vs baseline: 1.0196x; 1.0196x over previous
//
#include <hip/hip_runtime.h>

#define DTC 0.2f
#define EPSC 1e-8f

// sw layout (per-block LDS):
//   [0..7]    dlf[j]  (dl-MLP output per neighbor slot, bo folded in)
//   family f in {an=0, rn=1, rb=2} at base 16+f*112:
//     [+0..31]  sorted knots t = -bi/wi (ascending)
//     [+32..64] SufW[i] = sum_{m>=i} wi*wo  (SufW[32]=0)
//     [+65..97] SufB[i] = sum_{m>=i} wo*bi  (SufB[32]=0)
//   [352..359] an_bo, rn_bo, rb_bo, adp0, adp1, eff_angle, border0, border3
// mono(x)+bo = -(SufW[i]*x + SufB[i]) + bo,  i = #{knots <= x}

__device__ __forceinline__ float mono_eval(const float* __restrict__ kn, float x) {
    int i = (kn[15] <= x) ? 16 : 0;
    i += (kn[i + 7] <= x) ? 8 : 0;
    i += (kn[i + 3] <= x) ? 4 : 0;
    i += (kn[i + 1] <= x) ? 2 : 0;
    i += (kn[i] <= x) ? 1 : 0;
    return -fmaf(kn[32 + i], x, kn[65 + i]);
}

__global__ __launch_bounds__(256, 6) void sfm_fused(
    const float* __restrict__ ego, const float* __restrict__ nei,
    const float* __restrict__ border, const float* __restrict__ adp,
    const float* __restrict__ eang,
    const float* __restrict__ an_wi, const float* __restrict__ an_bi,
    const float* __restrict__ an_wo, const float* __restrict__ an_bo,
    const float* __restrict__ rn_wi, const float* __restrict__ rn_bi,
    const float* __restrict__ rn_wo, const float* __restrict__ rn_bo,
    const float* __restrict__ rb_wi, const float* __restrict__ rb_bi,
    const float* __restrict__ rb_wo, const float* __restrict__ rb_bo,
    const float* __restrict__ dl_wi, const float* __restrict__ dl_bi,
    const float* __restrict__ dl_wo, const float* __restrict__ dl_bo,
    float* __restrict__ out, int Bn)
{
    __shared__ __align__(16) float sw[360];
    __shared__ __align__(16) float snei[4352];   // 32 rows x 136 floats (tile buf; init scratch)
    __shared__ __align__(16) float sego[1632];   // 32 rows x 51 floats
    __shared__ __align__(16) float sout[192];    // 32 rows x 6 floats

    int t = threadIdx.x;

    // ================= per-block init: knot tables + dur/dl + scalars ======
    // scratch layout in snei: tk[0..95] wiwo[96..191] wobi[192..287]
    //                         skn[288..383] ssw[384..479] ssb[480..575]
    if (t < 96) {
        int f = t >> 5, k = t & 31;
        const float* wip = (f == 0) ? an_wi : ((f == 1) ? rn_wi : rb_wi);
        const float* bip = (f == 0) ? an_bi : ((f == 1) ? rn_bi : rb_bi);
        const float* wop = (f == 0) ? an_wo : ((f == 1) ? rn_wo : rb_wo);
        float wi = wip[k], bi = bip[k], wo = wop[k];
        snei[t]       = -bi / wi;
        snei[96 + t]  = wi * wo;
        snei[192 + t] = wo * bi;
    }
    __syncthreads();
    if (t < 96) {
        int f = t >> 5, k = t & 31;
        float my = snei[t];
        int rank = 0;
        for (int m = 0; m < 32; ++m) {
            float o = snei[f * 32 + m];
            rank += (o < my || (o == my && m < k)) ? 1 : 0;
        }
        snei[288 + f * 32 + rank] = my;
        snei[384 + f * 32 + rank] = snei[96 + t];
        snei[480 + f * 32 + rank] = snei[192 + t];
    }
    __syncthreads();
    if (t < 96) {
        int f = t >> 5, p = t & 31;
        float sw_ = 0.f, sb_ = 0.f;
        for (int m = p; m < 32; ++m) { sw_ += snei[384 + f * 32 + m]; sb_ += snei[480 + f * 32 + m]; }
        int base = 16 + f * 112;
        sw[base + p]      = snei[288 + f * 32 + p];
        sw[base + 32 + p] = sw_;
        sw[base + 65 + p] = sb_;
        if (p == 0) { sw[base + 64] = 0.f; sw[base + 97] = 0.f; }
    }
    if (t >= 96 && t < 104) {
        int j = t - 96;
        const float* base = ego + 51;               // ego[1,0,0]
        float idv = base[2 * 17 + 8 + j];
        float dur = 0.f;
        for (int tt = 0; tt < 3; ++tt) {
            bool fo = false;
            for (int m = 0; m < 8; ++m) fo = fo || (idv == base[tt * 17 + 8 + m]);
            dur += fo ? 1.f : 0.f;
        }
        float acc = 0.f;
        for (int k = 0; k < 32; ++k)
            acc = fmaf(dl_wo[k], fmaxf(0.f, -fmaf(dl_wi[k], dur, dl_bi[k])), acc);
        sw[j] = acc + dl_bo[0];
    }
    if (t == 104) sw[352] = an_bo[0];
    if (t == 105) sw[353] = rn_bo[0];
    if (t == 106) sw[354] = rb_bo[0];
    if (t == 107) sw[355] = adp[0];
    if (t == 108) sw[356] = adp[1];
    if (t == 109) sw[357] = eang[0];
    if (t == 110) sw[358] = border[0];
    if (t == 111) sw[359] = border[3];
    __syncthreads();

    // ================= persistent tile loop ================================
    int l   = t & 7;         // neighbor slot
    int r32 = t >> 3;        // row within tile
    long long nTiles = ((long long)Bn + 31) >> 5;

    for (long long tt = blockIdx.x; tt < nTiles; tt += gridDim.x) {
        // ---- coalesced staging (float4) ----
        {
            const float4* nsrc = (const float4*)nei + tt * 1088;
            float4* nd = (float4*)snei;
#pragma unroll
            for (int i = 0; i < 5; ++i) {
                int idx = t + 256 * i;
                if (idx < 1088 && tt * 1088 + idx < (long long)Bn * 34) nd[idx] = nsrc[idx];
            }
            const float4* esrc = (const float4*)ego + tt * 408;
            float4* ed = (float4*)sego;
#pragma unroll
            for (int i = 0; i < 2; ++i) {
                int idx = t + 256 * i;
                if (idx < 408 && tt * 408 + idx < ((long long)Bn * 51) / 4) ed[idx] = esrc[idx];
            }
        }
        __syncthreads();

        long long row = tt * 32 + r32;
        if (row < Bn) {
            const float* eg = sego + 51 * r32 + 34;
            float g0 = eg[0], g1 = eg[1], g2 = eg[2], g3 = eg[3], g4 = eg[4], g5 = eg[5];

            const float* nr = snei + 136 * r32 + 17 * l + 2;
            float nx = nr[0], ny = nr[1], vx = nr[2], vy = nr[3];

            float Rx = nx - g2, Ry = ny - g3;
            float rr = sqrtf(Rx * Rx + Ry * Ry);
            float ax = fmaf(vx, DTC, Rx), ay = fmaf(vy, DTC, Ry);
            float wx = vx * DTC, wy = vy * DTC;
            float bb = sqrtf(rr + ax * ax + ay * ay - wx * wx - wy * wy) * 0.5f;

            float an_bo_v = sw[352], rn_bo_v = sw[353], rb_bo_v = sw[354];
            float p0 = sw[355], p1 = sw[356], ang = sw[357];
            float rb0 = g3 - sw[358], rb1 = g3 - sw[359];
            float rbn0 = fabsf(rb0), rbn1 = fabsf(rb1);

            float fA = mono_eval(sw + 16, rr) + an_bo_v;
            float fR = mono_eval(sw + 128, bb) + rn_bo_v;
            float xb = (l == 1) ? rbn1 : rbn0;
            float vB = 0.f;
            if (l < 2) vB = mono_eval(sw + 240, xb) + rb_bo_v;
            int lb = (t & 63) & ~7;
            float vB0 = __shfl(vB, lb + 0, 64);
            float vB1 = __shfl(vB, lb + 1, 64);

            float elen = sqrtf(g4 * g4 + g5 * g5);
            float ex = g4 / elen, ey = g5 / elen;
            float na = fmaxf(sqrtf(ex * ex + ey * ey), EPSC);

            float axs = 0.f, ays = 0.f;
#define CLAMP_ADD(VX, VY)                                                   \
            {                                                               \
                float _vx = (VX), _vy = (VY);                               \
                float _nv = fmaxf(sqrtf(_vx * _vx + _vy * _vy), EPSC);      \
                float _c = (ex * _vx + ey * _vy) / (na * _nv);              \
                if (fabsf(_c) > ang) { axs += _vx; ays += _vy; }            \
            }

            float mfx = (nx == 0.f) ? 0.f : 1.f;
            float mfy = (ny == 0.f) ? 0.f : 1.f;

            { float coef = fA / rr * sw[l];  CLAMP_ADD(coef * Rx * mfx, coef * Ry * mfy); }
            { float coef = fR / rr;          CLAMP_ADD(coef * Rx * mfx, coef * Ry * mfy); }

#pragma unroll
            for (int m = 1; m < 8; m <<= 1) {
                axs += __shfl_xor(axs, m, 64);
                ays += __shfl_xor(ays, m, 64);
            }

            if (l == 0) {
                float dvn = sqrtf(g3 * g3 + g4 * g4);
                CLAMP_ADD((p1 * dvn - g3) / p0, -g4 / p0);
                CLAMP_ADD(0.f, vB0 * (rb0 / rbn0));
                CLAMP_ADD(0.f, vB1 * (rb1 / rbn1));

                float vxo = fmaf(axs, DTC, g2);
                float vyo = fmaf(ays, DTC, g3);
                float* op = sout + 6 * r32;
                op[0] = fmaf(vxo, DTC, g0);
                op[1] = fmaf(vyo, DTC, g1);
                op[2] = vxo; op[3] = vyo;
                op[4] = axs; op[5] = ays;
            }
#undef CLAMP_ADD
        }
        __syncthreads();

        // ---- coalesced output store (48 float4 per tile) ----
        if (t < 48) {
            long long o4 = tt * 48 + t;
            if (o4 < ((long long)Bn * 6) / 4) ((float4*)out)[o4] = ((const float4*)sout)[t];
        }
        __syncthreads();
    }
}

extern "C" void kernel_launch(void* const* d_in, const int* in_sizes, int n_in,
                              void* d_out, int out_size, void* d_ws, size_t ws_size,
                              hipStream_t stream) {
    const float* ego    = (const float*)d_in[0];
    const float* nei    = (const float*)d_in[1];
    const float* border = (const float*)d_in[2];
    const float* adp    = (const float*)d_in[3];
    const float* eang   = (const float*)d_in[4];
    const float* an_wi  = (const float*)d_in[5];
    const float* an_bi  = (const float*)d_in[6];
    const float* an_wo  = (const float*)d_in[7];
    const float* an_bo  = (const float*)d_in[8];
    const float* rn_wi  = (const float*)d_in[9];
    const float* rn_bi  = (const float*)d_in[10];
    const float* rn_wo  = (const float*)d_in[11];
    const float* rn_bo  = (const float*)d_in[12];
    const float* rb_wi  = (const float*)d_in[13];
    const float* rb_bi  = (const float*)d_in[14];
    const float* rb_wo  = (const float*)d_in[15];
    const float* rb_bo  = (const float*)d_in[16];
    const float* dl_wi  = (const float*)d_in[17];
    const float* dl_bi  = (const float*)d_in[18];
    const float* dl_wo  = (const float*)d_in[19];
    const float* dl_bo  = (const float*)d_in[20];
    float* out = (float*)d_out;
    (void)d_ws; (void)ws_size;

    int Bn = in_sizes[0] / (3 * 17);

    // persistent grid: 6 blocks/CU x 256 CUs (LDS-capped residency)
    sfm_fused<<<1536, 256, 0, stream>>>(ego, nei, border, adp, eang,
                                        an_wi, an_bi, an_wo, an_bo,
                                        rn_wi, rn_bi, rn_wo, rn_bo,
                                        rb_wi, rb_bi, rb_wo, rb_bo,
                                        dl_wi, dl_bi, dl_wo, dl_bo,
                                        out, Bn);
}

// Round 6
// 282.601 us; speedup vs baseline: 1.0250x; 1.0053x over previous
//
#include <hip/hip_runtime.h>

#define DTC 0.2f
#define EPSC 1e-8f

// sw layout (per-block LDS):
//   [0..7]    dlf[j]  (dl-MLP output per neighbor slot, bo folded in)
//   family f in {an=0, rn=1, rb=2} at base 16+f*112:
//     [+0..31]  sorted knots t = -bi/wi (ascending)
//     [+32..64] SufW[i] = sum_{m>=i} wi*wo  (SufW[32]=0)
//     [+65..97] SufB[i] = sum_{m>=i} wo*bi  (SufB[32]=0)
//   [352..359] an_bo, rn_bo, rb_bo, adp0, adp1, eff_angle, border0, border3
// mono(x)+bo = -(SufW[i]*x + SufB[i]) + bo,  i = #{knots <= x}

__device__ __forceinline__ float mono_eval(const float* __restrict__ kn, float x) {
    int i = (kn[15] <= x) ? 16 : 0;
    i += (kn[i + 7] <= x) ? 8 : 0;
    i += (kn[i + 3] <= x) ? 4 : 0;
    i += (kn[i + 1] <= x) ? 2 : 0;
    i += (kn[i] <= x) ? 1 : 0;
    return -fmaf(kn[32 + i], x, kn[65 + i]);
}

// 256 threads = 32 lane-groups of 8; each thread handles lane l of 4 rows.
// All 20 global loads per thread are issued before any dependent use; no
// per-tile barriers — waves run free after init.
__global__ __launch_bounds__(256) void sfm_fused(
    const float* __restrict__ ego, const float* __restrict__ nei,
    const float* __restrict__ border, const float* __restrict__ adp,
    const float* __restrict__ eang,
    const float* __restrict__ an_wi, const float* __restrict__ an_bi,
    const float* __restrict__ an_wo, const float* __restrict__ an_bo,
    const float* __restrict__ rn_wi, const float* __restrict__ rn_bi,
    const float* __restrict__ rn_wo, const float* __restrict__ rn_bo,
    const float* __restrict__ rb_wi, const float* __restrict__ rb_bi,
    const float* __restrict__ rb_wo, const float* __restrict__ rb_bo,
    const float* __restrict__ dl_wi, const float* __restrict__ dl_bi,
    const float* __restrict__ dl_wo, const float* __restrict__ dl_bo,
    float* __restrict__ out, int Bn)
{
    __shared__ __align__(16) float sw[360];
    __shared__ __align__(16) float scr[576];

    int t = threadIdx.x;

    // ---- per-block init: knot tables + dur/dl + scalars -------------------
    if (t < 96) {
        int f = t >> 5, k = t & 31;
        const float* wip = (f == 0) ? an_wi : ((f == 1) ? rn_wi : rb_wi);
        const float* bip = (f == 0) ? an_bi : ((f == 1) ? rn_bi : rb_bi);
        const float* wop = (f == 0) ? an_wo : ((f == 1) ? rn_wo : rb_wo);
        float wi = wip[k], bi = bip[k], wo = wop[k];
        scr[t]       = -bi / wi;
        scr[96 + t]  = wi * wo;
        scr[192 + t] = wo * bi;
    }
    __syncthreads();
    if (t < 96) {
        int f = t >> 5, k = t & 31;
        float my = scr[t];
        int rank = 0;
        for (int m = 0; m < 32; ++m) {
            float o = scr[f * 32 + m];
            rank += (o < my || (o == my && m < k)) ? 1 : 0;
        }
        scr[288 + f * 32 + rank] = my;
        scr[384 + f * 32 + rank] = scr[96 + t];
        scr[480 + f * 32 + rank] = scr[192 + t];
    }
    __syncthreads();
    if (t < 96) {
        int f = t >> 5, p = t & 31;
        float sw_ = 0.f, sb_ = 0.f;
        for (int m = p; m < 32; ++m) { sw_ += scr[384 + f * 32 + m]; sb_ += scr[480 + f * 32 + m]; }
        int base = 16 + f * 112;
        sw[base + p]      = scr[288 + f * 32 + p];
        sw[base + 32 + p] = sw_;
        sw[base + 65 + p] = sb_;
        if (p == 0) { sw[base + 64] = 0.f; sw[base + 97] = 0.f; }
    }
    if (t >= 96 && t < 104) {
        int j = t - 96;
        const float* base = ego + 51;               // ego[1,0,0]
        float idv = base[2 * 17 + 8 + j];
        float dur = 0.f;
        for (int tt = 0; tt < 3; ++tt) {
            bool fo = false;
            for (int m = 0; m < 8; ++m) fo = fo || (idv == base[tt * 17 + 8 + m]);
            dur += fo ? 1.f : 0.f;
        }
        float acc = 0.f;
        for (int k = 0; k < 32; ++k)
            acc = fmaf(dl_wo[k], fmaxf(0.f, -fmaf(dl_wi[k], dur, dl_bi[k])), acc);
        sw[j] = acc + dl_bo[0];
    }
    if (t == 104) sw[352] = an_bo[0];
    if (t == 105) sw[353] = rn_bo[0];
    if (t == 106) sw[354] = rb_bo[0];
    if (t == 107) sw[355] = adp[0];
    if (t == 108) sw[356] = adp[1];
    if (t == 109) sw[357] = eang[0];
    if (t == 110) sw[358] = border[0];
    if (t == 111) sw[359] = border[3];
    __syncthreads();

    int l  = t & 7;                         // neighbor slot
    int g  = t >> 3;                        // lane-group (row within quartet)
    long long base_row = (long long)blockIdx.x * 128 + g;

    // ---- batched loads: 4 rows x (1 ego + 4 nei) = 20 independent loads ---
    float egv[4], nx[4], ny[4], vx[4], vy[4];
#pragma unroll
    for (int i = 0; i < 4; ++i) {
        long long row = base_row + 32 * i;
        long long rc = (row < Bn) ? row : (Bn - 1);
        egv[i] = ego[rc * 51 + 34 + ((l < 6) ? l : 0)];
        const float* nr = nei + rc * 136 + 17 * l + 2;
        nx[i] = nr[0]; ny[i] = nr[1]; vx[i] = nr[2]; vy[i] = nr[3];
    }

    float an_bo_v = sw[352], rn_bo_v = sw[353], rb_bo_v = sw[354];
    float p0 = sw[355], p1 = sw[356], ang = sw[357];
    float bor0 = sw[358], bor3 = sw[359];
    float dlf_l = sw[l];
    int lb = (t & 63) & ~7;

#pragma unroll
    for (int i = 0; i < 4; ++i) {
        long long row = base_row + 32 * i;
        if (row >= Bn) break;

        float g0 = __shfl(egv[i], lb + 0, 64);
        float g1 = __shfl(egv[i], lb + 1, 64);
        float g2 = __shfl(egv[i], lb + 2, 64);
        float g3 = __shfl(egv[i], lb + 3, 64);
        float g4 = __shfl(egv[i], lb + 4, 64);
        float g5 = __shfl(egv[i], lb + 5, 64);

        float Rx = nx[i] - g2, Ry = ny[i] - g3;
        float rr = sqrtf(Rx * Rx + Ry * Ry);
        float ax = fmaf(vx[i], DTC, Rx), ay = fmaf(vy[i], DTC, Ry);
        float wx = vx[i] * DTC, wy = vy[i] * DTC;
        float bb = sqrtf(rr + ax * ax + ay * ay - wx * wx - wy * wy) * 0.5f;

        float rb0 = g3 - bor0, rb1 = g3 - bor3;
        float rbn0 = fabsf(rb0), rbn1 = fabsf(rb1);

        float fA = mono_eval(sw + 16, rr) + an_bo_v;
        float fR = mono_eval(sw + 128, bb) + rn_bo_v;
        float xb = (l == 1) ? rbn1 : rbn0;
        float vB = 0.f;
        if (l < 2) vB = mono_eval(sw + 240, xb) + rb_bo_v;
        float vB0 = __shfl(vB, lb + 0, 64);
        float vB1 = __shfl(vB, lb + 1, 64);

        float elen = sqrtf(g4 * g4 + g5 * g5);
        float ex = g4 / elen, ey = g5 / elen;
        float na = fmaxf(sqrtf(ex * ex + ey * ey), EPSC);

        float axs = 0.f, ays = 0.f;
#define CLAMP_ADD(VX, VY)                                                   \
        {                                                                   \
            float _vx = (VX), _vy = (VY);                                   \
            float _nv = fmaxf(sqrtf(_vx * _vx + _vy * _vy), EPSC);          \
            float _c = (ex * _vx + ey * _vy) / (na * _nv);                  \
            if (fabsf(_c) > ang) { axs += _vx; ays += _vy; }                \
        }

        float mfx = (nx[i] == 0.f) ? 0.f : 1.f;
        float mfy = (ny[i] == 0.f) ? 0.f : 1.f;

        { float coef = fA / rr * dlf_l;  CLAMP_ADD(coef * Rx * mfx, coef * Ry * mfy); }
        { float coef = fR / rr;          CLAMP_ADD(coef * Rx * mfx, coef * Ry * mfy); }

#pragma unroll
        for (int m = 1; m < 8; m <<= 1) {
            axs += __shfl_xor(axs, m, 64);
            ays += __shfl_xor(ays, m, 64);
        }

        if (l == 0) {
            float dvn = sqrtf(g3 * g3 + g4 * g4);
            CLAMP_ADD((p1 * dvn - g3) / p0, -g4 / p0);
            CLAMP_ADD(0.f, vB0 * (rb0 / rbn0));
            CLAMP_ADD(0.f, vB1 * (rb1 / rbn1));

            float vxo = fmaf(axs, DTC, g2);
            float vyo = fmaf(ays, DTC, g3);
            float* op = out + row * 6;
            op[0] = fmaf(vxo, DTC, g0);
            op[1] = fmaf(vyo, DTC, g1);
            op[2] = vxo; op[3] = vyo;
            op[4] = axs; op[5] = ays;
        }
#undef CLAMP_ADD
    }
}

extern "C" void kernel_launch(void* const* d_in, const int* in_sizes, int n_in,
                              void* d_out, int out_size, void* d_ws, size_t ws_size,
                              hipStream_t stream) {
    const float* ego    = (const float*)d_in[0];
    const float* nei    = (const float*)d_in[1];
    const float* border = (const float*)d_in[2];
    const float* adp    = (const float*)d_in[3];
    const float* eang   = (const float*)d_in[4];
    const float* an_wi  = (const float*)d_in[5];
    const float* an_bi  = (const float*)d_in[6];
    const float* an_wo  = (const float*)d_in[7];
    const float* an_bo  = (const float*)d_in[8];
    const float* rn_wi  = (const float*)d_in[9];
    const float* rn_bi  = (const float*)d_in[10];
    const float* rn_wo  = (const float*)d_in[11];
    const float* rn_bo  = (const float*)d_in[12];
    const float* rb_wi  = (const float*)d_in[13];
    const float* rb_bi  = (const float*)d_in[14];
    const float* rb_wo  = (const float*)d_in[15];
    const float* rb_bo  = (const float*)d_in[16];
    const float* dl_wi  = (const float*)d_in[17];
    const float* dl_bi  = (const float*)d_in[18];
    const float* dl_wo  = (const float*)d_in[19];
    const float* dl_bo  = (const float*)d_in[20];
    float* out = (float*)d_out;
    (void)d_ws; (void)ws_size;

    int Bn = in_sizes[0] / (3 * 17);

    int grid = (Bn + 127) / 128;    // 4 rows per thread, 128 rows per block
    sfm_fused<<<grid, 256, 0, stream>>>(ego, nei, border, adp, eang,
                                        an_wi, an_bi, an_wo, an_bo,
                                        rn_wi, rn_bi, rn_wo, rn_bo,
                                        rb_wi, rb_bi, rb_wo, rb_bo,
                                        dl_wi, dl_bi, dl_wo, dl_bo,
                                        out, Bn);
}

// Round 7
// 278.807 us; speedup vs baseline: 1.0390x; 1.0136x over previous
//
#include <hip/hip_runtime.h>

#define DTC 0.2f
#define EPSC 1e-8f

// ws float layout:
//   [0..7]    dlf[j]  (dl-MLP output per neighbor slot, bo folded in)
//   family f in {an=0, rn=1, rb=2} at base B=16+f*112:
//     [B..B+31]    sorted knots t = -bi/wi  (ascending)
//     [B+32..B+64] SufW[i] = sum_{m>=i} wi*wo over sorted order (SufW[32]=0)
//     [B+65..B+97] SufB[i] = sum_{m>=i} wo*bi                  (SufB[32]=0)
// mono(x) = -(SufW[i]*x + SufB[i]) + bo,  i = #{knots <= x}  (5-step search)

__global__ __launch_bounds__(128) void sfm_pre(
    const float* __restrict__ ego,
    const float* __restrict__ an_wi, const float* __restrict__ an_bi, const float* __restrict__ an_wo,
    const float* __restrict__ rn_wi, const float* __restrict__ rn_bi, const float* __restrict__ rn_wo,
    const float* __restrict__ rb_wi, const float* __restrict__ rb_bi, const float* __restrict__ rb_wo,
    const float* __restrict__ dl_wi, const float* __restrict__ dl_bi,
    const float* __restrict__ dl_wo, const float* __restrict__ dl_bo,
    float* __restrict__ ws)
{
    __shared__ float tk[96], wiwo[96], wobi[96], skn[96], ssw[96], ssb[96];
    int t = threadIdx.x;
    if (t < 96) {
        int f = t >> 5, k = t & 31;
        const float* wip = (f == 0) ? an_wi : ((f == 1) ? rn_wi : rb_wi);
        const float* bip = (f == 0) ? an_bi : ((f == 1) ? rn_bi : rb_bi);
        const float* wop = (f == 0) ? an_wo : ((f == 1) ? rn_wo : rb_wo);
        float wi = wip[k], bi = bip[k], wo = wop[k];
        tk[t]   = -bi / wi;
        wiwo[t] = wi * wo;
        wobi[t] = wo * bi;
    }
    __syncthreads();
    if (t < 96) {
        int f = t >> 5, k = t & 31;
        float my = tk[t];
        int rank = 0;
        for (int m = 0; m < 32; ++m) {
            float o = tk[f * 32 + m];
            rank += (o < my || (o == my && m < k)) ? 1 : 0;
        }
        skn[f * 32 + rank] = my;
        ssw[f * 32 + rank] = wiwo[t];
        ssb[f * 32 + rank] = wobi[t];
    }
    __syncthreads();
    if (t < 96) {
        int f = t >> 5, p = t & 31;
        float sw_ = 0.f, sb_ = 0.f;
        for (int m = p; m < 32; ++m) { sw_ += ssw[f * 32 + m]; sb_ += ssb[f * 32 + m]; }
        int base = 16 + f * 112;
        ws[base + p]      = skn[f * 32 + p];
        ws[base + 32 + p] = sw_;
        ws[base + 65 + p] = sb_;
        if (p == 0) { ws[base + 64] = 0.f; ws[base + 97] = 0.f; }
    }
    if (t >= 96 && t < 104) {
        int j = t - 96;
        const float* base = ego + 51;
        float idv = base[2 * 17 + 8 + j];
        float dur = 0.f;
        for (int tt = 0; tt < 3; ++tt) {
            bool fo = false;
            for (int m = 0; m < 8; ++m) fo = fo || (idv == base[tt * 17 + 8 + m]);
            dur += fo ? 1.f : 0.f;
        }
        float acc = 0.f;
        for (int k = 0; k < 32; ++k)
            acc = fmaf(dl_wo[k], fmaxf(0.f, -fmaf(dl_wi[k], dur, dl_bi[k])), acc);
        ws[j] = acc + dl_bo[0];
    }
}

__device__ __forceinline__ float mono_eval(const float* __restrict__ kn, float x) {
    int i = (kn[15] <= x) ? 16 : 0;
    i += (kn[i + 7] <= x) ? 8 : 0;
    i += (kn[i + 3] <= x) ? 4 : 0;
    i += (kn[i + 1] <= x) ? 2 : 0;
    i += (kn[i] <= x) ? 1 : 0;
    return -fmaf(kn[32 + i], x, kn[65 + i]);
}

// ---------------------------------------------------------------------------
// Main: 8 lanes per row (one per neighbor record). 256 threads = 32 rows.
// ---------------------------------------------------------------------------
__global__ __launch_bounds__(256) void sfm_main(
    const float* __restrict__ ego, const float* __restrict__ nei,
    const float* __restrict__ border, const float* __restrict__ adp,
    const float* __restrict__ eang,
    const float* __restrict__ an_bo, const float* __restrict__ rn_bo,
    const float* __restrict__ rb_bo,
    const float* __restrict__ wsrc,
    float* __restrict__ out, int Bn)
{
    __shared__ float sw[360];
    int t = threadIdx.x;
    for (int i = t; i < 352; i += 256) sw[i] = wsrc[i];
    if (t == 0) sw[352] = an_bo[0];
    if (t == 1) sw[353] = rn_bo[0];
    if (t == 2) sw[354] = rb_bo[0];
    if (t == 3) sw[355] = adp[0];
    if (t == 4) sw[356] = adp[1];
    if (t == 5) sw[357] = eang[0];
    if (t == 6) sw[358] = border[0];
    if (t == 7) sw[359] = border[3];
    __syncthreads();

    int l = t & 7;                                  // record index
    long long row = (long long)blockIdx.x * 32 + (t >> 3);
    if (row >= Bn) return;

    // ego fields g0..g5 via lanes 0..5 + broadcast
    float egv = 0.f;
    if (l < 6) egv = ego[row * 51 + 34 + l];
    int lb = (t & 63) & ~7;
    float g0 = __shfl(egv, lb + 0, 64);
    float g1 = __shfl(egv, lb + 1, 64);
    float g2 = __shfl(egv, lb + 2, 64);
    float g3 = __shfl(egv, lb + 3, 64);
    float g4 = __shfl(egv, lb + 4, 64);
    float g5 = __shfl(egv, lb + 5, 64);

    // this lane's neighbor record fields 2..5
    const float* nr = nei + row * 136 + l * 17 + 2;
    float nx = nr[0], ny = nr[1], vx = nr[2], vy = nr[3];

    float Rx = nx - g2, Ry = ny - g3;
    float rr = sqrtf(Rx * Rx + Ry * Ry);
    float ax = fmaf(vx, DTC, Rx), ay = fmaf(vy, DTC, Ry);
    float wx = vx * DTC, wy = vy * DTC;
    float bb = sqrtf(rr + ax * ax + ay * ay - wx * wx - wy * wy) * 0.5f;

    float an_bo_v = sw[352], rn_bo_v = sw[353], rb_bo_v = sw[354];
    float p0 = sw[355], p1 = sw[356], ang = sw[357];
    float rb0 = g3 - sw[358], rb1 = g3 - sw[359];
    float rbn0 = fabsf(rb0), rbn1 = fabsf(rb1);

    // MLP evals via knot search (bases: an=16, rn=128, rb=240)
    float fA = mono_eval(sw + 16, rr) + an_bo_v;
    float fR = mono_eval(sw + 128, bb) + rn_bo_v;
    float xb = (l == 1) ? rbn1 : rbn0;
    float vB = 0.f;
    if (l < 2) vB = mono_eval(sw + 240, xb) + rb_bo_v;
    float vB0 = __shfl(vB, lb + 0, 64);
    float vB1 = __shfl(vB, lb + 1, 64);

    // e = normalize(ego_last[4:6])
    float elen = sqrtf(g4 * g4 + g5 * g5);
    float ex = g4 / elen, ey = g5 / elen;
    float na = fmaxf(sqrtf(ex * ex + ey * ey), EPSC);

    float axs = 0.f, ays = 0.f;
#define CLAMP_ADD(VX, VY)                                                   \
    {                                                                       \
        float _vx = (VX), _vy = (VY);                                       \
        float _nv = fmaxf(sqrtf(_vx * _vx + _vy * _vy), EPSC);              \
        float _c = (ex * _vx + ey * _vy) / (na * _nv);                      \
        if (fabsf(_c) > ang) { axs += _vx; ays += _vy; }                    \
    }

    float mfx = (nx == 0.f) ? 0.f : 1.f;
    float mfy = (ny == 0.f) ? 0.f : 1.f;

    { // f_attr for this record
        float coef = fA / rr * sw[l];               // dlf factor
        CLAMP_ADD(coef * Rx * mfx, coef * Ry * mfy);
    }
    { // f_repu for this record
        float coef = fR / rr;
        CLAMP_ADD(coef * Rx * mfx, coef * Ry * mfy);
    }

    // reduce axs/ays over the 8 lanes of the row
#pragma unroll
    for (int m = 1; m < 8; m <<= 1) {
        axs += __shfl_xor(axs, m, 64);
        ays += __shfl_xor(ays, m, 64);
    }

    if (l == 0) {
        // f_dest
        float dvn = sqrtf(g3 * g3 + g4 * g4);
        CLAMP_ADD((p1 * dvn - g3) / p0, -g4 / p0);
        // f_bor: (0, mono_rb(|rbv|) * sign(rbv)) for the two borders
        CLAMP_ADD(0.f, vB0 * (rb0 / rbn0));
        CLAMP_ADD(0.f, vB1 * (rb1 / rbn1));

        float vxo = fmaf(axs, DTC, g2);
        float vyo = fmaf(ays, DTC, g3);
        float* op = out + row * 6;
        op[0] = fmaf(vxo, DTC, g0);
        op[1] = fmaf(vyo, DTC, g1);
        op[2] = vxo; op[3] = vyo;
        op[4] = axs; op[5] = ays;
    }
#undef CLAMP_ADD
}

extern "C" void kernel_launch(void* const* d_in, const int* in_sizes, int n_in,
                              void* d_out, int out_size, void* d_ws, size_t ws_size,
                              hipStream_t stream) {
    const float* ego    = (const float*)d_in[0];
    const float* nei    = (const float*)d_in[1];
    const float* border = (const float*)d_in[2];
    const float* adp    = (const float*)d_in[3];
    const float* eang   = (const float*)d_in[4];
    const float* an_wi  = (const float*)d_in[5];
    const float* an_bi  = (const float*)d_in[6];
    const float* an_wo  = (const float*)d_in[7];
    const float* an_bo  = (const float*)d_in[8];
    const float* rn_wi  = (const float*)d_in[9];
    const float* rn_bi  = (const float*)d_in[10];
    const float* rn_wo  = (const float*)d_in[11];
    const float* rn_bo  = (const float*)d_in[12];
    const float* rb_wi  = (const float*)d_in[13];
    const float* rb_bi  = (const float*)d_in[14];
    const float* rb_wo  = (const float*)d_in[15];
    const float* rb_bo  = (const float*)d_in[16];
    const float* dl_wi  = (const float*)d_in[17];
    const float* dl_bi  = (const float*)d_in[18];
    const float* dl_wo  = (const float*)d_in[19];
    const float* dl_bo  = (const float*)d_in[20];
    float* out = (float*)d_out;
    float* ws  = (float*)d_ws;

    int Bn = in_sizes[0] / (3 * 17);

    sfm_pre<<<1, 128, 0, stream>>>(ego,
                                   an_wi, an_bi, an_wo,
                                   rn_wi, rn_bi, rn_wo,
                                   rb_wi, rb_bi, rb_wo,
                                   dl_wi, dl_bi, dl_wo, dl_bo, ws);

    int grid = (Bn + 31) / 32;
    sfm_main<<<grid, 256, 0, stream>>>(ego, nei, border, adp, eang,
                                       an_bo, rn_bo, rb_bo,
                                       ws, out, Bn);
}